// Round 5
// baseline (282.126 us; speedup 1.0000x reference)
//
#include <hip/hip_runtime.h>
#include <hip/hip_bf16.h>

typedef __bf16 bf16;
typedef __bf16 bf16x8 __attribute__((ext_vector_type(8)));
typedef __bf16 bf16x4 __attribute__((ext_vector_type(4)));
typedef float f32x4 __attribute__((ext_vector_type(4)));

#define CDIM 1280

static __device__ __forceinline__ f32x4 mfma16(bf16x8 a, bf16x8 b, f32x4 c) {
  return __builtin_amdgcn_mfma_f32_16x16x32_bf16(a, b, c, 0, 0, 0);
}

static __device__ __forceinline__ void gload_lds(const bf16* g, bf16* l) {
  __builtin_amdgcn_global_load_lds(
      (const __attribute__((address_space(1))) void*)g,
      (__attribute__((address_space(3))) void*)l, 16, 0, 0);
}

static __device__ __forceinline__ float fexp2(float x) {
#if __has_builtin(__builtin_amdgcn_exp2f)
  return __builtin_amdgcn_exp2f(x);
#else
  return __expf(x * 0.6931471805599453f);
#endif
}

// ---- fused f32 -> bf16 conversion for hidden + 4 weights ----
__global__ __launch_bounds__(256) void cvt_all(const float* __restrict__ h,
                                               const float* __restrict__ wq,
                                               const float* __restrict__ wk,
                                               const float* __restrict__ wv,
                                               const float* __restrict__ wo,
                                               bf16* __restrict__ hb, bf16* __restrict__ wqb,
                                               bf16* __restrict__ wkb, bf16* __restrict__ wvb,
                                               bf16* __restrict__ wob) {
  int id = blockIdx.x * 256 + threadIdx.x;  // float4 index, total 2949120
  const float* src; bf16* dst; int off;
  if (id < 1310720) { src = h; dst = hb; off = id; }
  else {
    int t = id - 1310720;
    int w = t / 409600; off = t % 409600;
    src = (w == 0) ? wq : (w == 1) ? wk : (w == 2) ? wv : wo;
    dst = (w == 0) ? wqb : (w == 1) ? wkb : (w == 2) ? wvb : wob;
  }
  float4 v = reinterpret_cast<const float4*>(src)[off];
  bf16x4 o;
  o[0] = (bf16)v.x; o[1] = (bf16)v.y; o[2] = (bf16)v.z; o[3] = (bf16)v.w;
  reinterpret_cast<bf16x4*>(dst)[off] = o;
}

// ---- fused QKV projection: X(4096x1280) x [Wq|Wk|Wv]^T ----
__global__ __launch_bounds__(256) void qkv_gemm(const bf16* __restrict__ X,
                                                const bf16* __restrict__ Wq,
                                                const bf16* __restrict__ Wk,
                                                const bf16* __restrict__ Wv,
                                                const float* __restrict__ mask,
                                                bf16* __restrict__ Qb,
                                                bf16* __restrict__ Kb,
                                                bf16* __restrict__ Vt) {
  __shared__ bf16 Al[128 * 64];
  __shared__ bf16 Bl[128 * 64];
  const int tid = threadIdx.x, lane = tid & 63, wv = tid >> 6;
  const int lr = lane & 15, lg = lane >> 4;
  const int xb = blockIdx.x, by = blockIdx.y;
  const int wsel = xb / 10;            // 0=Q 1=K 2=V
  const int cb = (xb % 10) * 128;
  const bf16* W = (wsel == 0) ? Wq : (wsel == 1) ? Wk : Wv;
  const int strow = tid >> 3, stchk = tid & 7;
  f32x4 acc[4][4] = {};
  for (int kt = 0; kt < 20; ++kt) {
    __syncthreads();
#pragma unroll
    for (int i = 0; i < 4; ++i) {
      gload_lds(X + (size_t)(by * 128 + i * 32 + strow) * CDIM + kt * 64 + stchk * 8,
                &Al[(i * 256 + tid) * 8]);
      gload_lds(W + (size_t)(cb + i * 32 + strow) * CDIM + kt * 64 + stchk * 8,
                &Bl[(i * 256 + tid) * 8]);
    }
    __syncthreads();
#pragma unroll
    for (int kk = 0; kk < 2; ++kk) {
      bf16x8 a[4], b[4];
#pragma unroll
      for (int i = 0; i < 4; ++i) {
        a[i] = *(const bf16x8*)&Al[((wv >> 1) * 64 + i * 16 + lr) * 64 + kk * 32 + lg * 8];
        b[i] = *(const bf16x8*)&Bl[((wv & 1) * 64 + i * 16 + lr) * 64 + kk * 32 + lg * 8];
      }
#pragma unroll
      for (int i = 0; i < 4; ++i)
#pragma unroll
        for (int j = 0; j < 4; ++j)
          acc[i][j] = mfma16(a[i], b[j], acc[i][j]);
    }
  }
  const int rbase = by * 128 + (wv >> 1) * 64;
  const int cbase = cb + (wv & 1) * 64;
  if (wsel == 2) {  // V -> Vt[bh][d][key], gated rows >= 2048
#pragma unroll
    for (int i = 0; i < 4; ++i)
#pragma unroll
      for (int r = 0; r < 4; ++r) {
        const int row = rbase + i * 16 + lg * 4 + r;
        const float g = (row >= 2048) ? mask[row - 2048] : 1.0f;
        const int br = row >> 11, bb = (row >> 10) & 1, key = row & 1023;
#pragma unroll
        for (int j = 0; j < 4; ++j) {
          const int col = cbase + j * 16 + lr;
          const int hh = col >> 6, d = col & 63;
          Vt[(size_t)(br * 40 + bb * 20 + hh) * 65536 + d * 1024 + key] =
              (bf16)(acc[i][j][r] * g);
        }
      }
  } else {
    bf16* Y = (wsel == 0) ? Qb : Kb;
    const bool gated = (wsel == 1);
#pragma unroll
    for (int i = 0; i < 4; ++i)
#pragma unroll
      for (int r = 0; r < 4; ++r) {
        const int row = rbase + i * 16 + lg * 4 + r;
        const float g = (gated && row >= 2048) ? mask[row - 2048] : 1.0f;
#pragma unroll
        for (int j = 0; j < 4; ++j)
          Y[(size_t)row * CDIM + cbase + j * 16 + lr] = (bf16)(acc[i][j][r] * g);
      }
  }
}

// ---- flash attention v5: wave owns all 64 q, kt-split 4-way, zero-LDS main loop ----
// Operands come straight from L2 (K/V per (b,h) = 512 KB, L2-resident).
// Per-branch cross-wave merge of (m,l,O) partials via 34 KB LDS, f32 exact.
__global__ __launch_bounds__(256) void attn_kernel(const bf16* __restrict__ Q,
                                                   const bf16* __restrict__ K,
                                                   const bf16* __restrict__ Vt,
                                                   bf16* __restrict__ Mg) {
  __shared__ f32x4 Obuf[2048];          // 32 KB: [w*2+dtp][qs][lg*16+lr]
  __shared__ float mbuf[4][4][16];      // [w][qs][lr]
  __shared__ float lbuf[4][4][16];
  const int tid = threadIdx.x, lane = tid & 63, wv = tid >> 6;
  const int lr = lane & 15, lg = lane >> 4;
  // bijective XCD-chunked swizzle (nwg = 1280, 1280 % 8 == 0)
  const int bid = blockIdx.x;
  const int sb = (bid & 7) * 160 + (bid >> 3);
  const int qt = sb & 31, hh = (sb >> 5) % 20, b = sb / 640;
  const int qrow = b * 2048 + qt * 64;

  // Q fragments for all 4 q-subtiles, pre-scaled to exp2 domain. 32 VGPR.
  bf16x8 qf[2][4];
  {
    const float SL2E = 0.125f * 1.4426950408889634f;
#pragma unroll
    for (int qs = 0; qs < 4; ++qs) {
      const bf16* qp = Q + (size_t)(qrow + qs * 16 + lr) * CDIM + hh * 64 + lg * 8;
      bf16x8 r0 = *(const bf16x8*)qp;
      bf16x8 r1 = *(const bf16x8*)(qp + 32);
#pragma unroll
      for (int j = 0; j < 8; ++j) {
        qf[0][qs][j] = (bf16)((float)r0[j] * SL2E);
        qf[1][qs][j] = (bf16)((float)r1[j] * SL2E);
      }
    }
  }

  float m_[4], l_[4];
  f32x4 O_[4][4];     // [dt][qs], cols q = qs*16+lr, rows d = dt*16+lg*4+e
  f32x4 Ofin[4];      // merged, qs = wv only
#pragma unroll
  for (int qs = 0; qs < 4; ++qs) { m_[qs] = -INFINITY; l_[qs] = 0.f; }
#pragma unroll
  for (int dt = 0; dt < 4; ++dt) {
    Ofin[dt] = f32x4{};
#pragma unroll
    for (int qs = 0; qs < 4; ++qs) O_[dt][qs] = f32x4{};
  }

  for (int br = 0; br < 2; ++br) {
    const bf16* Kbr = K + ((size_t)br * 2048 + b * 1024) * CDIM + hh * 64;
    const bf16* Vbr = Vt + (size_t)(br * 40 + b * 20 + hh) * 65536;

    for (int j = 0; j < 4; ++j) {
      const int keyb = (wv + j * 4) * 64;

      // K fragments: 8 x b128 direct from L2. row=key=kb*16+lr, k=d
      bf16x8 kf[4][2];
#pragma unroll
      for (int kb = 0; kb < 4; ++kb) {
        const bf16* kp = Kbr + (size_t)(keyb + kb * 16 + lr) * CDIM + lg * 8;
        kf[kb][0] = *(const bf16x8*)kp;
        kf[kb][1] = *(const bf16x8*)(kp + 32);
      }
      // V fragments (A-operand, key-permuted): per dt 4 x b64, offset-folded
      bf16x8 va[4][2];
#pragma unroll
      for (int dt = 0; dt < 4; ++dt) {
        const bf16* vp = Vbr + (size_t)(dt * 16 + lr) * 1024 + keyb + lg * 4;
        bf16x4 t0 = *(const bf16x4*)vp;
        bf16x4 t1 = *(const bf16x4*)(vp + 16);
        bf16x4 t2 = *(const bf16x4*)(vp + 32);
        bf16x4 t3 = *(const bf16x4*)(vp + 48);
#pragma unroll
        for (int e = 0; e < 4; ++e) {
          va[dt][0][e] = t0[e]; va[dt][0][4 + e] = t1[e];
          va[dt][1][e] = t2[e]; va[dt][1][4 + e] = t3[e];
        }
      }

#pragma unroll
      for (int qs = 0; qs < 4; ++qs) {
        // S^T[key][q], keys kb*16+lg*4+r, q = qs*16+lr
        f32x4 z[4];
        __builtin_amdgcn_s_setprio(1);
#pragma unroll
        for (int kb = 0; kb < 4; ++kb) {
          f32x4 t = {};
          t = mfma16(kf[kb][0], qf[0][qs], t);
          t = mfma16(kf[kb][1], qf[1][qs], t);
          z[kb] = t;
        }
        __builtin_amdgcn_s_setprio(0);

        float pm = -INFINITY;
#pragma unroll
        for (int kb = 0; kb < 4; ++kb)
#pragma unroll
          for (int r = 0; r < 4; ++r) pm = fmaxf(pm, z[kb][r]);
        pm = fmaxf(pm, __shfl_xor(pm, 16, 64));
        pm = fmaxf(pm, __shfl_xor(pm, 32, 64));

        float p[16], rs = 0.f;
        if (__all(pm <= m_[qs] + 8.f)) {   // defer-max: P <= 2^8, exact merge later
#pragma unroll
          for (int kb = 0; kb < 4; ++kb)
#pragma unroll
            for (int r = 0; r < 4; ++r) {
              float e = fexp2(z[kb][r] - m_[qs]);
              p[kb * 4 + r] = e; rs += e;
            }
          rs += __shfl_xor(rs, 16, 64);
          rs += __shfl_xor(rs, 32, 64);
          l_[qs] += rs;
        } else {
          const float mn = fmaxf(m_[qs], pm);
          const float al = fexp2(m_[qs] - mn);
#pragma unroll
          for (int kb = 0; kb < 4; ++kb)
#pragma unroll
            for (int r = 0; r < 4; ++r) {
              float e = fexp2(z[kb][r] - mn);
              p[kb * 4 + r] = e; rs += e;
            }
          rs += __shfl_xor(rs, 16, 64);
          rs += __shfl_xor(rs, 32, 64);
          l_[qs] = l_[qs] * al + rs;
          m_[qs] = mn;
#pragma unroll
          for (int dt = 0; dt < 4; ++dt) {
            O_[dt][qs][0] *= al; O_[dt][qs][1] *= al;
            O_[dt][qs][2] *= al; O_[dt][qs][3] *= al;
          }
        }

        // P as PV B-fragment (key-permuted, verified R4): pb0[e]=p[e], pb1[e]=p[8+e]
        bf16x8 pb0, pb1;
#pragma unroll
        for (int e = 0; e < 8; ++e) { pb0[e] = (bf16)p[e]; pb1[e] = (bf16)p[8 + e]; }

        __builtin_amdgcn_s_setprio(1);
#pragma unroll
        for (int dt = 0; dt < 4; ++dt) {
          O_[dt][qs] = mfma16(va[dt][0], pb0, O_[dt][qs]);
          O_[dt][qs] = mfma16(va[dt][1], pb1, O_[dt][qs]);
        }
        __builtin_amdgcn_s_setprio(0);
      }
    }

    // ---- cross-wave flash merge (exact, f32). Wave wv owns qs = wv. ----
    __syncthreads();
    if (lg == 0) {
#pragma unroll
      for (int qs = 0; qs < 4; ++qs) { mbuf[wv][qs][lr] = m_[qs]; lbuf[wv][qs][lr] = l_[qs]; }
    }
#pragma unroll
    for (int dtp = 0; dtp < 2; ++dtp)
#pragma unroll
      for (int qs = 0; qs < 4; ++qs)
        Obuf[((wv * 2 + dtp) * 4 + qs) * 64 + lg * 16 + lr] = O_[dtp][qs];
    __syncthreads();

    float aw0, aw1, aw2, aw3, invL;
    {
      float m0 = mbuf[0][wv][lr], m1 = mbuf[1][wv][lr];
      float m2 = mbuf[2][wv][lr], m3 = mbuf[3][wv][lr];
      float Mx = fmaxf(fmaxf(m0, m1), fmaxf(m2, m3));
      aw0 = fexp2(m0 - Mx); aw1 = fexp2(m1 - Mx);
      aw2 = fexp2(m2 - Mx); aw3 = fexp2(m3 - Mx);
      float L = lbuf[0][wv][lr] * aw0 + lbuf[1][wv][lr] * aw1 +
                lbuf[2][wv][lr] * aw2 + lbuf[3][wv][lr] * aw3;
      invL = 1.0f / L;
    }
#pragma unroll
    for (int dtp = 0; dtp < 2; ++dtp) {
      f32x4 acc = Obuf[((0 * 2 + dtp) * 4 + wv) * 64 + lg * 16 + lr] * aw0
                + Obuf[((1 * 2 + dtp) * 4 + wv) * 64 + lg * 16 + lr] * aw1
                + Obuf[((2 * 2 + dtp) * 4 + wv) * 64 + lg * 16 + lr] * aw2
                + Obuf[((3 * 2 + dtp) * 4 + wv) * 64 + lg * 16 + lr] * aw3;
      Ofin[dtp] += acc * invL;
    }
    __syncthreads();
#pragma unroll
    for (int dtp = 0; dtp < 2; ++dtp)
#pragma unroll
      for (int qs = 0; qs < 4; ++qs)
        Obuf[((wv * 2 + dtp) * 4 + qs) * 64 + lg * 16 + lr] = O_[2 + dtp][qs];
    __syncthreads();
#pragma unroll
    for (int dtp = 0; dtp < 2; ++dtp) {
      f32x4 acc = Obuf[((0 * 2 + dtp) * 4 + wv) * 64 + lg * 16 + lr] * aw0
                + Obuf[((1 * 2 + dtp) * 4 + wv) * 64 + lg * 16 + lr] * aw1
                + Obuf[((2 * 2 + dtp) * 4 + wv) * 64 + lg * 16 + lr] * aw2
                + Obuf[((3 * 2 + dtp) * 4 + wv) * 64 + lg * 16 + lr] * aw3;
      Ofin[2 + dtp] += acc * invL;
    }

    if (br == 0) {  // reset for branch 2
#pragma unroll
      for (int qs = 0; qs < 4; ++qs) { m_[qs] = -INFINITY; l_[qs] = 0.f; }
#pragma unroll
      for (int dt = 0; dt < 4; ++dt)
#pragma unroll
        for (int qs = 0; qs < 4; ++qs) O_[dt][qs] = f32x4{};
    }
  }

  // store: wave wv owns q = qrow + wv*16 + lr; d = dt*16 + lg*4 + e
#pragma unroll
  for (int dt = 0; dt < 4; ++dt) {
    bf16x4 o4;
    o4[0] = (bf16)Ofin[dt][0]; o4[1] = (bf16)Ofin[dt][1];
    o4[2] = (bf16)Ofin[dt][2]; o4[3] = (bf16)Ofin[dt][3];
    *(bf16x4*)&Mg[(size_t)(qrow + wv * 16 + lr) * CDIM + hh * 64 + dt * 16 + lg * 4] = o4;
  }
}

// ---- final projection: Mg(4096x1280) x Wo^T + bias -> f32 out ----
__global__ __launch_bounds__(256) void out_gemm(const bf16* __restrict__ X,
                                                const bf16* __restrict__ W,
                                                const float* __restrict__ bias,
                                                float* __restrict__ Y) {
  __shared__ bf16 Al[128 * 64];
  __shared__ bf16 Bl[128 * 64];
  const int tid = threadIdx.x, lane = tid & 63, wv = tid >> 6;
  const int lr = lane & 15, lg = lane >> 4;
  const int cb = blockIdx.x * 128, by = blockIdx.y;
  const int strow = tid >> 3, stchk = tid & 7;
  f32x4 acc[4][4] = {};
  for (int kt = 0; kt < 20; ++kt) {
    __syncthreads();
#pragma unroll
    for (int i = 0; i < 4; ++i) {
      gload_lds(X + (size_t)(by * 128 + i * 32 + strow) * CDIM + kt * 64 + stchk * 8,
                &Al[(i * 256 + tid) * 8]);
      gload_lds(W + (size_t)(cb + i * 32 + strow) * CDIM + kt * 64 + stchk * 8,
                &Bl[(i * 256 + tid) * 8]);
    }
    __syncthreads();
#pragma unroll
    for (int kk = 0; kk < 2; ++kk) {
      bf16x8 a[4], b[4];
#pragma unroll
      for (int i = 0; i < 4; ++i) {
        a[i] = *(const bf16x8*)&Al[((wv >> 1) * 64 + i * 16 + lr) * 64 + kk * 32 + lg * 8];
        b[i] = *(const bf16x8*)&Bl[((wv & 1) * 64 + i * 16 + lr) * 64 + kk * 32 + lg * 8];
      }
#pragma unroll
      for (int i = 0; i < 4; ++i)
#pragma unroll
        for (int j = 0; j < 4; ++j)
          acc[i][j] = mfma16(a[i], b[j], acc[i][j]);
    }
  }
  const int rbase = by * 128 + (wv >> 1) * 64;
  const int cbase = cb + (wv & 1) * 64;
#pragma unroll
  for (int i = 0; i < 4; ++i)
#pragma unroll
    for (int r = 0; r < 4; ++r) {
      const int row = rbase + i * 16 + lg * 4 + r;
#pragma unroll
      for (int j = 0; j < 4; ++j) {
        const int col = cbase + j * 16 + lr;
        Y[(size_t)row * CDIM + col] = acc[i][j][r] + bias[col];
      }
    }
}

extern "C" void kernel_launch(void* const* d_in, const int* in_sizes, int n_in,
                              void* d_out, int out_size, void* d_ws, size_t ws_size,
                              hipStream_t stream) {
  const float* hidden = (const float*)d_in[0];
  const float* mask   = (const float*)d_in[1];
  const float* Wq     = (const float*)d_in[2];
  const float* Wk     = (const float*)d_in[3];
  const float* Wv     = (const float*)d_in[4];
  const float* Wo     = (const float*)d_in[5];
  const float* bo     = (const float*)d_in[6];
  float* out = (float*)d_out;

  char* ws = (char*)d_ws;
  bf16* hb  = (bf16*)(ws);             // 4096x1280 (aliased as Mg after projections)
  bf16* wqb = (bf16*)(ws + 10485760);
  bf16* wkb = (bf16*)(ws + 13762560);
  bf16* wvb = (bf16*)(ws + 17039360);
  bf16* wob = (bf16*)(ws + 20316160);
  bf16* Qb  = (bf16*)(ws + 23592960);  // 4096x1280
  bf16* Kb  = (bf16*)(ws + 34078720);  // 4096x1280 (bg rows 0..2047, face gated 2048..4095)
  bf16* Vt  = (bf16*)(ws + 44564480);  // [80][64][1024] transposed V, gated
  bf16* Mg  = hb;

  cvt_all<<<dim3(11520), 256, 0, stream>>>(hidden, Wq, Wk, Wv, Wo, hb, wqb, wkb, wvb, wob);
  qkv_gemm<<<dim3(30, 32), 256, 0, stream>>>(hb, wqb, wkb, wvb, mask, Qb, Kb, Vt);
  attn_kernel<<<dim3(1280), 256, 0, stream>>>(Qb, Kb, Vt, Mg);
  out_gemm<<<dim3(10, 32), 256, 0, stream>>>(Mg, wob, bo, out);
}

// Round 6
// 206.961 us; speedup vs baseline: 1.3632x; 1.3632x over previous
//
#include <hip/hip_runtime.h>
#include <hip/hip_bf16.h>

typedef __bf16 bf16;
typedef __bf16 bf16x8 __attribute__((ext_vector_type(8)));
typedef __bf16 bf16x4 __attribute__((ext_vector_type(4)));
typedef float f32x4 __attribute__((ext_vector_type(4)));

#define CDIM 1280

static __device__ __forceinline__ f32x4 mfma16(bf16x8 a, bf16x8 b, f32x4 c) {
  return __builtin_amdgcn_mfma_f32_16x16x32_bf16(a, b, c, 0, 0, 0);
}

static __device__ __forceinline__ void gload_lds(const bf16* g, bf16* l) {
  __builtin_amdgcn_global_load_lds(
      (const __attribute__((address_space(1))) void*)g,
      (__attribute__((address_space(3))) void*)l, 16, 0, 0);
}

static __device__ __forceinline__ float fexp2(float x) {
#if __has_builtin(__builtin_amdgcn_exp2f)
  return __builtin_amdgcn_exp2f(x);
#else
  return __expf(x * 0.6931471805599453f);
#endif
}

// ---- fused f32 -> bf16 conversion for hidden + 4 weights ----
__global__ __launch_bounds__(256) void cvt_all(const float* __restrict__ h,
                                               const float* __restrict__ wq,
                                               const float* __restrict__ wk,
                                               const float* __restrict__ wv,
                                               const float* __restrict__ wo,
                                               bf16* __restrict__ hb, bf16* __restrict__ wqb,
                                               bf16* __restrict__ wkb, bf16* __restrict__ wvb,
                                               bf16* __restrict__ wob) {
  int id = blockIdx.x * 256 + threadIdx.x;  // float4 index, total 2949120
  const float* src; bf16* dst; int off;
  if (id < 1310720) { src = h; dst = hb; off = id; }
  else {
    int t = id - 1310720;
    int w = t / 409600; off = t % 409600;
    src = (w == 0) ? wq : (w == 1) ? wk : (w == 2) ? wv : wo;
    dst = (w == 0) ? wqb : (w == 1) ? wkb : (w == 2) ? wvb : wob;
  }
  float4 v = reinterpret_cast<const float4*>(src)[off];
  bf16x4 o;
  o[0] = (bf16)v.x; o[1] = (bf16)v.y; o[2] = (bf16)v.z; o[3] = (bf16)v.w;
  reinterpret_cast<bf16x4*>(dst)[off] = o;
}

// ---- fused QKV projection: X(4096x1280) x [Wq|Wk|Wv]^T ----
// V written to VtP[bh][kt][d][j]: key order permuted by sigma (j = s*32+g*8+t*4+u
// holds key = s*32+t*16+g*4+u), gated, via LDS transpose for coalesced stores.
__global__ __launch_bounds__(256) void qkv_gemm(const bf16* __restrict__ X,
                                                const bf16* __restrict__ Wq,
                                                const bf16* __restrict__ Wk,
                                                const bf16* __restrict__ Wv,
                                                const float* __restrict__ mask,
                                                bf16* __restrict__ Qb,
                                                bf16* __restrict__ Kb,
                                                bf16* __restrict__ Vt) {
  __shared__ bf16 SM[2][128 * 64];
  bf16* Al = SM[0];
  bf16* Bl = SM[1];
  const int tid = threadIdx.x, lane = tid & 63, wv = tid >> 6;
  const int lr = lane & 15, lg = lane >> 4;
  const int xb = blockIdx.x, by = blockIdx.y;
  const int wsel = xb / 10;            // 0=Q 1=K 2=V
  const int cb = (xb % 10) * 128;
  const bf16* W = (wsel == 0) ? Wq : (wsel == 1) ? Wk : Wv;
  const int strow = tid >> 3, stchk = tid & 7;
  f32x4 acc[4][4] = {};
  for (int kt = 0; kt < 20; ++kt) {
    __syncthreads();
#pragma unroll
    for (int i = 0; i < 4; ++i) {
      gload_lds(X + (size_t)(by * 128 + i * 32 + strow) * CDIM + kt * 64 + stchk * 8,
                &Al[(i * 256 + tid) * 8]);
      gload_lds(W + (size_t)(cb + i * 32 + strow) * CDIM + kt * 64 + stchk * 8,
                &Bl[(i * 256 + tid) * 8]);
    }
    __syncthreads();
#pragma unroll
    for (int kk = 0; kk < 2; ++kk) {
      bf16x8 a[4], b[4];
#pragma unroll
      for (int i = 0; i < 4; ++i) {
        a[i] = *(const bf16x8*)&Al[((wv >> 1) * 64 + i * 16 + lr) * 64 + kk * 32 + lg * 8];
        b[i] = *(const bf16x8*)&Bl[((wv & 1) * 64 + i * 16 + lr) * 64 + kk * 32 + lg * 8];
      }
#pragma unroll
      for (int i = 0; i < 4; ++i)
#pragma unroll
        for (int j = 0; j < 4; ++j)
          acc[i][j] = mfma16(a[i], b[j], acc[i][j]);
    }
  }
  if (wsel == 2) {
    // ---- V epilogue: gate, permute keys, LDS-transpose, coalesced store ----
    __syncthreads();                 // Al/Bl reads done; reuse as T[128col][128row]
    bf16* T = &SM[0][0];
#pragma unroll
    for (int i = 0; i < 4; ++i)
#pragma unroll
      for (int r = 0; r < 4; ++r) {
        const int lrow = (wv >> 1) * 64 + i * 16 + lg * 4 + r;   // local key row
        const int row = by * 128 + lrow;
        const float g = (row >= 2048) ? mask[row - 2048] : 1.0f;
        const int rb = lrow >> 6, kpos = lrow & 63;
        const int jp = (kpos & 32) + ((kpos >> 2) & 3) * 8 + ((kpos >> 4) & 1) * 4 + (kpos & 3);
#pragma unroll
        for (int j = 0; j < 4; ++j) {
          const int col = (wv & 1) * 64 + j * 16 + lr;           // local channel
          T[col * 128 + ((rb * 64 + jp) ^ ((col & 7) << 3))] = (bf16)(acc[i][j][r] * g);
        }
      }
    __syncthreads();
#pragma unroll
    for (int q = 0; q < 8; ++q) {
      const int col = (tid >> 4) + q * 16;
      const int rc = tid & 15, rb = rc >> 3, rc8 = rc & 7;
      bf16x8 vv = *(const bf16x8*)&T[col * 128 + rb * 64 + ((rc8 ^ (col & 7)) << 3)];
      const int gcol = cb + col, hh = gcol >> 6, d = gcol & 63;
      const int kb64 = by * 2 + rb;
      const int br = kb64 >> 5, bb = (kb64 >> 4) & 1, kt = kb64 & 15;
      *(bf16x8*)&Vt[(size_t)(((br * 40 + bb * 20 + hh) * 16 + kt) * 64 + d) * 64 + rc8 * 8] = vv;
    }
  } else {
    const int rbase = by * 128 + (wv >> 1) * 64;
    const int cbase = cb + (wv & 1) * 64;
    bf16* Y = (wsel == 0) ? Qb : Kb;
    const bool gated = (wsel == 1);
#pragma unroll
    for (int i = 0; i < 4; ++i)
#pragma unroll
      for (int r = 0; r < 4; ++r) {
        const int row = rbase + i * 16 + lg * 4 + r;
        const float g = (gated && row >= 2048) ? mask[row - 2048] : 1.0f;
#pragma unroll
        for (int j = 0; j < 4; ++j)
          Y[(size_t)row * CDIM + cbase + j * 16 + lr] = (bf16)(acc[i][j][r] * g);
      }
  }
}

// ---- flash attention: R3 staging skeleton + in-register P via permuted-V layout ----
__global__ __launch_bounds__(256) void attn_kernel(const bf16* __restrict__ Q,
                                                   const bf16* __restrict__ K,
                                                   const bf16* __restrict__ Vt,
                                                   bf16* __restrict__ Mg) {
  __shared__ bf16 Kl[2][64 * 64];
  __shared__ bf16 Vl[2][64 * 64];
  const int tid = threadIdx.x, lane = tid & 63, wv = tid >> 6;
  const int lr = lane & 15, lg = lane >> 4;
  // bijective XCD-chunked swizzle (nwg = 1280, 1280 % 8 == 0)
  const int bid = blockIdx.x;
  const int sb = (bid & 7) * 160 + (bid >> 3);
  const int qt = sb & 31, hh = (sb >> 5) % 20, b = sb / 640;
  const int qrow = b * 2048 + qt * 64 + wv * 16;
  const int strow = tid >> 3, stchk = tid & 7;
  const int sw = lr & 7;

  const bf16* Kb0 = K + (size_t)(b * 1024) * CDIM + hh * 64;
  const bf16* Vb0 = Vt + (size_t)(b * 20 + hh) * 65536;

  // Q fragments (B-operand: col=q=lr over this wave's 16 rows), exp2-domain scale
  bf16x8 qf0, qf1;
  {
    const float SL2E = 0.125f * 1.4426950408889634f;
    const bf16* qp = Q + (size_t)(qrow + lr) * CDIM + hh * 64 + lg * 8;
    bf16x8 r0 = *(const bf16x8*)qp;
    bf16x8 r1 = *(const bf16x8*)(qp + 32);
#pragma unroll
    for (int j = 0; j < 8; ++j) {
      qf0[j] = (bf16)((float)r0[j] * SL2E);
      qf1[j] = (bf16)((float)r1[j] * SL2E);
    }
  }

  auto stage = [&](int t, int buf) {
    const int br = t >> 4, kt = t & 15;
    const bf16* Kp = Kb0 + (size_t)br * 2048 * CDIM;
    const bf16* Vp = Vb0 + (size_t)br * 40 * 65536;
#pragma unroll
    for (int i = 0; i < 2; ++i) {
      const int row = i * 32 + strow;
      gload_lds(Kp + (size_t)(kt * 64 + row) * CDIM + (stchk ^ (row & 7)) * 8,
                &Kl[buf][(i * 256 + tid) * 8]);
      gload_lds(Vp + kt * 4096 + row * 64 + (stchk ^ (row & 7)) * 8,
                &Vl[buf][(i * 256 + tid) * 8]);
    }
  };

  float m = -INFINITY, l = 0.f;
  f32x4 O[4] = {};
  f32x4 Ofin[4] = {};

  stage(0, 0);
  __syncthreads();

  for (int t = 0; t < 32; ++t) {
    const int cur = t & 1;
    if (t < 31) stage(t + 1, cur ^ 1);  // issue-early: latency hides under compute

    // S^T[key][q] = K . Q^T   (lane owns q = lr; keys kb*16 + lg*4 + r)
    f32x4 z[4];
    __builtin_amdgcn_s_setprio(1);
#pragma unroll
    for (int kb = 0; kb < 4; ++kb) {
      const int row = kb * 16 + lr;
      bf16x8 k0 = *(const bf16x8*)&Kl[cur][row * 64 + (lg ^ sw) * 8];
      bf16x8 k1 = *(const bf16x8*)&Kl[cur][row * 64 + ((4 + lg) ^ sw) * 8];
      f32x4 zz = {};
      zz = mfma16(k0, qf0, zz);
      zz = mfma16(k1, qf1, zz);
      z[kb] = zz;
    }
    __builtin_amdgcn_s_setprio(0);

    // online softmax in exp2 domain, defer-max (THR=8 -> P <= 256), in-lane alpha
    float pm = -INFINITY;
#pragma unroll
    for (int kb = 0; kb < 4; ++kb)
#pragma unroll
      for (int r = 0; r < 4; ++r) pm = fmaxf(pm, z[kb][r]);
    pm = fmaxf(pm, __shfl_xor(pm, 16, 64));
    pm = fmaxf(pm, __shfl_xor(pm, 32, 64));

    float p[16], rs = 0.f;
    if (__all(pm <= m + 8.f)) {
#pragma unroll
      for (int kb = 0; kb < 4; ++kb)
#pragma unroll
        for (int r = 0; r < 4; ++r) {
          float e = fexp2(z[kb][r] - m);
          p[kb * 4 + r] = e; rs += e;
        }
      rs += __shfl_xor(rs, 16, 64);
      rs += __shfl_xor(rs, 32, 64);
      l += rs;
    } else {
      const float mn = fmaxf(m, pm);
      const float al = fexp2(m - mn);
#pragma unroll
      for (int kb = 0; kb < 4; ++kb)
#pragma unroll
        for (int r = 0; r < 4; ++r) {
          float e = fexp2(z[kb][r] - mn);
          p[kb * 4 + r] = e; rs += e;
        }
      rs += __shfl_xor(rs, 16, 64);
      rs += __shfl_xor(rs, 32, 64);
      l = l * al + rs;
      m = mn;
#pragma unroll
      for (int dt = 0; dt < 4; ++dt) {
        O[dt][0] *= al; O[dt][1] *= al; O[dt][2] *= al; O[dt][3] *= al;
      }
    }

    // P stays in registers as PV B-fragment (key-permuted): pb_s[e] = p[s*8+e]
    bf16x8 pb0, pb1;
#pragma unroll
    for (int e = 0; e < 8; ++e) { pb0[e] = (bf16)p[e]; pb1[e] = (bf16)p[8 + e]; }

    // O^T[d][q] += V . P : A-frag rows d = dt*16+lr, contiguous b128 (layout-permuted)
    __builtin_amdgcn_s_setprio(1);
#pragma unroll
    for (int dt = 0; dt < 4; ++dt) {
      const int row = dt * 16 + lr;
      bf16x8 v0 = *(const bf16x8*)&Vl[cur][row * 64 + (lg ^ sw) * 8];
      bf16x8 v1 = *(const bf16x8*)&Vl[cur][row * 64 + ((4 + lg) ^ sw) * 8];
      O[dt] = mfma16(v0, pb0, O[dt]);
      O[dt] = mfma16(v1, pb1, O[dt]);
    }
    __builtin_amdgcn_s_setprio(0);

    if (t == 15 || t == 31) {  // end of branch: merge with 1/l (in-lane, q = lr)
      const float invl = 1.0f / l;
#pragma unroll
      for (int dt = 0; dt < 4; ++dt) {
        Ofin[dt][0] += O[dt][0] * invl; Ofin[dt][1] += O[dt][1] * invl;
        Ofin[dt][2] += O[dt][2] * invl; Ofin[dt][3] += O[dt][3] * invl;
      }
      if (t == 15) {
        m = -INFINITY; l = 0.f;
#pragma unroll
        for (int dt = 0; dt < 4; ++dt) O[dt] = f32x4{};
      }
    }
    __syncthreads();  // staged tile t+1 ready; buf[cur] free for overwrite
  }

  // store: lane holds q = qrow+lr, d = dt*16 + lg*4 + 0..3 -> b64 stores
#pragma unroll
  for (int dt = 0; dt < 4; ++dt) {
    bf16x4 o4;
    o4[0] = (bf16)Ofin[dt][0]; o4[1] = (bf16)Ofin[dt][1];
    o4[2] = (bf16)Ofin[dt][2]; o4[3] = (bf16)Ofin[dt][3];
    *(bf16x4*)&Mg[(size_t)(qrow + lr) * CDIM + hh * 64 + dt * 16 + lg * 4] = o4;
  }
}

// ---- final projection: Mg(4096x1280) x Wo^T + bias -> f32 out ----
__global__ __launch_bounds__(256) void out_gemm(const bf16* __restrict__ X,
                                                const bf16* __restrict__ W,
                                                const float* __restrict__ bias,
                                                float* __restrict__ Y) {
  __shared__ bf16 Al[128 * 64];
  __shared__ bf16 Bl[128 * 64];
  const int tid = threadIdx.x, lane = tid & 63, wv = tid >> 6;
  const int lr = lane & 15, lg = lane >> 4;
  const int cb = blockIdx.x * 128, by = blockIdx.y;
  const int strow = tid >> 3, stchk = tid & 7;
  f32x4 acc[4][4] = {};
  for (int kt = 0; kt < 20; ++kt) {
    __syncthreads();
#pragma unroll
    for (int i = 0; i < 4; ++i) {
      gload_lds(X + (size_t)(by * 128 + i * 32 + strow) * CDIM + kt * 64 + stchk * 8,
                &Al[(i * 256 + tid) * 8]);
      gload_lds(W + (size_t)(cb + i * 32 + strow) * CDIM + kt * 64 + stchk * 8,
                &Bl[(i * 256 + tid) * 8]);
    }
    __syncthreads();
#pragma unroll
    for (int kk = 0; kk < 2; ++kk) {
      bf16x8 a[4], b[4];
#pragma unroll
      for (int i = 0; i < 4; ++i) {
        a[i] = *(const bf16x8*)&Al[((wv >> 1) * 64 + i * 16 + lr) * 64 + kk * 32 + lg * 8];
        b[i] = *(const bf16x8*)&Bl[((wv & 1) * 64 + i * 16 + lr) * 64 + kk * 32 + lg * 8];
      }
#pragma unroll
      for (int i = 0; i < 4; ++i)
#pragma unroll
        for (int j = 0; j < 4; ++j)
          acc[i][j] = mfma16(a[i], b[j], acc[i][j]);
    }
  }
  const int rbase = by * 128 + (wv >> 1) * 64;
  const int cbase = cb + (wv & 1) * 64;
#pragma unroll
  for (int i = 0; i < 4; ++i)
#pragma unroll
    for (int r = 0; r < 4; ++r) {
      const int row = rbase + i * 16 + lg * 4 + r;
#pragma unroll
      for (int j = 0; j < 4; ++j) {
        const int col = cbase + j * 16 + lr;
        Y[(size_t)row * CDIM + col] = acc[i][j][r] + bias[col];
      }
    }
}

extern "C" void kernel_launch(void* const* d_in, const int* in_sizes, int n_in,
                              void* d_out, int out_size, void* d_ws, size_t ws_size,
                              hipStream_t stream) {
  const float* hidden = (const float*)d_in[0];
  const float* mask   = (const float*)d_in[1];
  const float* Wq     = (const float*)d_in[2];
  const float* Wk     = (const float*)d_in[3];
  const float* Wv     = (const float*)d_in[4];
  const float* Wo     = (const float*)d_in[5];
  const float* bo     = (const float*)d_in[6];
  float* out = (float*)d_out;

  char* ws = (char*)d_ws;
  bf16* hb  = (bf16*)(ws);             // 4096x1280 (aliased as Mg after projections)
  bf16* wqb = (bf16*)(ws + 10485760);
  bf16* wkb = (bf16*)(ws + 13762560);
  bf16* wvb = (bf16*)(ws + 17039360);
  bf16* wob = (bf16*)(ws + 20316160);
  bf16* Qb  = (bf16*)(ws + 23592960);  // 4096x1280
  bf16* Kb  = (bf16*)(ws + 34078720);  // 4096x1280 (bg rows 0..2047, face gated 2048..4095)
  bf16* Vt  = (bf16*)(ws + 44564480);  // [80 bh][16 kt][64 d][64 j] permuted V, gated
  bf16* Mg  = hb;

  cvt_all<<<dim3(11520), 256, 0, stream>>>(hidden, Wq, Wk, Wv, Wo, hb, wqb, wkb, wvb, wob);
  qkv_gemm<<<dim3(30, 32), 256, 0, stream>>>(hb, wqb, wkb, wvb, mask, Qb, Kb, Vt);
  attn_kernel<<<dim3(1280), 256, 0, stream>>>(Qb, Kb, Vt, Mg);
  out_gemm<<<dim3(10, 32), 256, 0, stream>>>(Mg, wob, bo, out);
}